// Round 3
// baseline (644.478 us; speedup 1.0000x reference)
//
#include <hip/hip_runtime.h>
#include <hip/hip_bf16.h>

// Problem dims (fixed by reference)
//   B=128, T=256, D_MODEL=128, D_INNER=256, D_STATE=16, D_CONV=4, DT_RANK=8
// I/O dtype: float32. This round: all-VALU fp32 compute (no MFMA) to bisect
// the round-2 failure; only xcpre/zact are bf16 (error budget <=1e-3 abs).
// Outputs: h (128,128,128) then x_skip (128,256,128), fp32, concatenated.

typedef __attribute__((ext_vector_type(4))) float f32x4;
using bf16 = __hip_bfloat16;

static __device__ __forceinline__ short f2s(float v) {
  union { bf16 b; short s; } u; u.b = (bf16)v; return u.s;
}
static __device__ __forceinline__ float s2f(short s) {
  union { short s; bf16 b; } u; u.s = s; return (float)u.b;
}

// ---------------------------------------------------------------------------
// VALU GEMM: C[row, gcol] = sum_k A[row,k] * W[gcol,k]   (W row-major N x K)
// Block: 32 rows x NCOLS cols, 256 threads. A-tile staged in LDS (single pass
// over full K). MODE 0: plain fp32 store to C (ldc), guarded by col<NSTORE
// (also guards W reads). MODE 1: in_proj epilogue -> bf16 xcpre (gc<256) /
// bf16 silu(z) (gc>=256).
// ---------------------------------------------------------------------------
template<int NCOLS, int K, int MODE, int NSTORE>
__global__ __launch_bounds__(256) void vgemm(const float* __restrict__ A,
                                             const float* __restrict__ W,
                                             float* __restrict__ C,
                                             short* __restrict__ xcpre,
                                             short* __restrict__ zact,
                                             int ldc) {
  constexpr int RPT = (32 * NCOLS) / 256;   // 16 (NCOLS=128) / 8 (NCOLS=64)
  __shared__ float At[32][K];
  const int m0  = blockIdx.x * 32;
  const int tid = threadIdx.x;
  for (int idx = tid; idx < 32 * K; idx += 256) {
    int r = idx / K, k = idx % K;
    At[r][k] = A[(size_t)(m0 + r) * K + k];
  }
  __syncthreads();
  const int col  = tid % NCOLS;
  const int r0   = (tid / NCOLS) * RPT;
  const int gcol = blockIdx.y * NCOLS + col;
  if (col < NSTORE) {
    float acc[RPT];
#pragma unroll
    for (int r = 0; r < RPT; ++r) acc[r] = 0.f;
    const float* Wrow = W + (size_t)gcol * K;
    for (int k = 0; k < K; k += 4) {
      f32x4 w = *(const f32x4*)(Wrow + k);
#pragma unroll
      for (int r = 0; r < RPT; ++r) {
        const float* a = &At[r0 + r][k];
        acc[r] += a[0] * w[0] + a[1] * w[1] + a[2] * w[2] + a[3] * w[3];
      }
    }
    if (MODE == 0) {
#pragma unroll
      for (int r = 0; r < RPT; ++r)
        C[(size_t)(m0 + r0 + r) * ldc + gcol] = acc[r];
    } else {
#pragma unroll
      for (int r = 0; r < RPT; ++r) {
        const int row = m0 + r0 + r;
        if (gcol < 256) {
          xcpre[(size_t)row * 256 + gcol] = f2s(acc[r]);
        } else {
          float v = acc[r];
          zact[(size_t)row * 256 + (gcol - 256)] = f2s(v / (1.f + __expf(-v)));
        }
      }
    }
  }
}

// ---------------------------------------------------------------------------
// Depthwise causal conv (width 4, cross-correlation) + bias + silu.
// xcpre (B*T,256) bf16 -> xc (B*T,256) fp32.
// ---------------------------------------------------------------------------
__global__ __launch_bounds__(256) void conv_silu(const short* __restrict__ xcpre,
                                                 const float* __restrict__ cw,
                                                 const float* __restrict__ cb,
                                                 float* __restrict__ xc) {
  int idx = blockIdx.x * 256 + threadIdx.x;   // (b,t,d), d fastest
  int d = idx & 255;
  int t = (idx >> 8) & 255;
  int b = idx >> 16;
  float acc = cb[d];
#pragma unroll
  for (int i = 0; i < 4; ++i) {
    int ts = t - 3 + i;
    if (ts >= 0)
      acc += s2f(xcpre[(size_t)(b * 256 + ts) * 256 + d]) * cw[d * 4 + i];
  }
  xc[idx] = acc / (1.f + __expf(-acc));
}

// ---------------------------------------------------------------------------
// Selective scan with fused delta = softplus(dt @ dt_proj_w^T + dt_proj_b).
// Block = (batch, half of d_inner), 128 threads, one d each. h[16] fp32 regs.
// xdbl cols 0..39 (dt|B|C) double-buffered in LDS; u/z register-prefetched.
// y written IN-PLACE over xc. y = (scan + u*D) * silu(z).
// ---------------------------------------------------------------------------
__global__ __launch_bounds__(128) void scan_k(const float* __restrict__ xdbl,
                                              float* __restrict__ xcy,
                                              const short* __restrict__ zact,
                                              const float* __restrict__ dtw,
                                              const float* __restrict__ dtb,
                                              const float* __restrict__ alog,
                                              const float* __restrict__ Dp) {
  const int b = blockIdx.x >> 1;
  const int d = (blockIdx.x & 1) * 128 + threadIdx.x;
  float A[16];
#pragma unroll
  for (int n = 0; n < 16; ++n) A[n] = -__expf(alog[d * 16 + n]);
  float wdt[8];
#pragma unroll
  for (int j = 0; j < 8; ++j) wdt[j] = dtw[d * 8 + j];
  const float bdt = dtb[d];
  const float Dv  = Dp[d];
  float h[16];
#pragma unroll
  for (int n = 0; n < 16; ++n) h[n] = 0.f;
  __shared__ float BC[2][40];
  const size_t rb = (size_t)b * 256;
  if (threadIdx.x < 40) BC[0][threadIdx.x] = xdbl[rb * 64 + threadIdx.x];
  float u_n = xcy[rb * 256 + d];
  float z_n = s2f(zact[rb * 256 + d]);
  for (int t = 0; t < 256; ++t) {
    __syncthreads();
    const size_t row = rb + t;
    if (t + 1 < 256 && threadIdx.x < 40)
      BC[(t + 1) & 1][threadIdx.x] = xdbl[(row + 1) * 64 + threadIdx.x];
    const float u = u_n, zs = z_n;
    if (t + 1 < 256) {
      u_n = xcy[(row + 1) * 256 + d];
      z_n = s2f(zact[(row + 1) * 256 + d]);
    }
    const float* S = BC[t & 1];     // [0..7]=dt, [8..23]=B, [24..39]=C
    float dacc = bdt;
#pragma unroll
    for (int j = 0; j < 8; ++j) dacc += S[j] * wdt[j];
    const float delta = (dacc > 20.f) ? dacc : log1pf(__expf(dacc));
    const float du = delta * u;
    float yt = 0.f;
#pragma unroll
    for (int n = 0; n < 16; ++n) {
      float dA = __expf(delta * A[n]);
      h[n] = dA * h[n] + du * S[8 + n];
      yt += h[n] * S[24 + n];
    }
    xcy[row * 256 + d] = (yt + u * Dv) * zs;
  }
}

// ---------------------------------------------------------------------------
// Transpose down_w (co,ci,k) -> WT[(k*128+ci)*128 + co] for coalesced reads.
// ---------------------------------------------------------------------------
__global__ __launch_bounds__(256) void prep_wcat(const float* __restrict__ dw,
                                                 float* __restrict__ wt) {
  int idx = blockIdx.x * 256 + threadIdx.x;   // 0..49151
  int co = idx & 127;
  int j  = idx >> 7;          // k*128+ci
  int k  = j >> 7;
  int ci = j & 127;
  wt[idx] = dw[(co * 128 + ci) * 3 + k];
}

// ---------------------------------------------------------------------------
// Fused strided down-conv: hd[b,to,co] = sum_{k,ci} h1[b,2to+k-1,ci]*w[co,ci,k]
// + db[co]. Block = (b, group of 8 'to'), 128 threads (one co each); the 17
// needed h1 time-rows staged in LDS; WT reads coalesced, 8x reused.
// ---------------------------------------------------------------------------
__global__ __launch_bounds__(128) void down_k(const float* __restrict__ h1,
                                              const float* __restrict__ wt,
                                              const float* __restrict__ db,
                                              float* __restrict__ hd) {
  const int b   = blockIdx.x >> 4;
  const int to0 = (blockIdx.x & 15) * 8;
  const int co  = threadIdx.x;
  __shared__ float hs[17][128];
  const int tbase = 2 * to0 - 1;
#pragma unroll
  for (int i = 0; i < 17; ++i) {
    int t = tbase + i;
    hs[i][co] = (t >= 0 && t < 256) ? h1[(size_t)(b * 256 + t) * 128 + co] : 0.f;
  }
  __syncthreads();
  float acc[8];
  const float bias = db[co];
#pragma unroll
  for (int r = 0; r < 8; ++r) acc[r] = bias;
  for (int j = 0; j < 384; ++j) {
    float w = wt[j * 128 + co];
    int k = j >> 7, ci = j & 127;
#pragma unroll
    for (int r = 0; r < 8; ++r) acc[r] += hs[2 * r + k][ci] * w;
  }
#pragma unroll
  for (int r = 0; r < 8; ++r)
    hd[(size_t)(b * 128 + to0 + r) * 128 + co] = acc[r];
}

// ---------------------------------------------------------------------------
// LayerNorm over last dim (128), eps 1e-5. One wave per row, 2 cols/thread.
// ---------------------------------------------------------------------------
__global__ __launch_bounds__(64) void ln_k(const float* __restrict__ hd,
                                           const float* __restrict__ g,
                                           const float* __restrict__ be,
                                           float* __restrict__ out) {
  int row = blockIdx.x;
  const float* r = hd + (size_t)row * 128;
  float v0 = r[threadIdx.x];
  float v1 = r[threadIdx.x + 64];
  float s = v0 + v1;
#pragma unroll
  for (int off = 32; off; off >>= 1) s += __shfl_xor(s, off);
  float mu = s * (1.0f / 128.0f);
  float d0 = v0 - mu, d1 = v1 - mu;
  float vs = d0 * d0 + d1 * d1;
#pragma unroll
  for (int off = 32; off; off >>= 1) vs += __shfl_xor(vs, off);
  float rstd = rsqrtf(vs * (1.0f / 128.0f) + 1e-5f);
  out[(size_t)row * 128 + threadIdx.x]      = d0 * rstd * g[threadIdx.x] + be[threadIdx.x];
  out[(size_t)row * 128 + threadIdx.x + 64] = d1 * rstd * g[threadIdx.x + 64] + be[threadIdx.x + 64];
}

// ---------------------------------------------------------------------------
// Workspace layout (bytes), peak 92,471,296:
//   xcpre bf16 [0, 16M)  | zact bf16 [16M, 32M) | xc fp32 [32M, 64M) (y in-place)
//   xdbl fp32 [64M, 72M) | h1 fp32 [72M, 88M)   | WT fp32 [88M, +192K)
// hd (16384x128 fp32) staged in d_out's x_skip half, consumed by LN before
// the final x_skip copy overwrites it.
// ---------------------------------------------------------------------------
static const size_t O_XCPRE = 0;
static const size_t O_ZACT  = 16777216;
static const size_t O_XC    = 33554432;
static const size_t O_XDBL  = 67108864;
static const size_t O_H1    = 75497472;
static const size_t O_WT    = 92274688;   // end 92,471,296

extern "C" void kernel_launch(void* const* d_in, const int* in_sizes, int n_in,
                              void* d_out, int out_size, void* d_ws, size_t ws_size,
                              hipStream_t stream) {
  const float* x    = (const float*)d_in[0];
  const float* ipw  = (const float*)d_in[1];
  const float* cw   = (const float*)d_in[2];
  const float* cb   = (const float*)d_in[3];
  const float* xpw  = (const float*)d_in[4];
  const float* dtw  = (const float*)d_in[5];
  const float* dtb  = (const float*)d_in[6];
  const float* alog = (const float*)d_in[7];
  const float* Dp   = (const float*)d_in[8];
  const float* opw  = (const float*)d_in[9];
  const float* dw   = (const float*)d_in[10];
  const float* db   = (const float*)d_in[11];
  const float* lng  = (const float*)d_in[12];
  const float* lnb  = (const float*)d_in[13];

  char*  ws    = (char*)d_ws;
  short* xcpre = (short*)(ws + O_XCPRE);
  short* zact  = (short*)(ws + O_ZACT);
  float* xc    = (float*)(ws + O_XC);     // becomes y in-place after scan
  float* xdbl  = (float*)(ws + O_XDBL);
  float* h1    = (float*)(ws + O_H1);
  float* wt    = (float*)(ws + O_WT);
  float* out   = (float*)d_out;
  float* hd    = out + 2097152;           // staged in x_skip half of d_out

  // 0. transpose down_w
  prep_wcat<<<192, 256, 0, stream>>>(dw, wt);
  // 1. in_proj (32768x512, K=128) -> bf16 xcpre (cols 0..255), bf16 silu(z)
  vgemm<128, 128, 1, 128><<<dim3(1024, 4), 256, 0, stream>>>(
      x, ipw, nullptr, xcpre, zact, 0);
  // 2. depthwise causal conv + silu -> xc (fp32)
  conv_silu<<<32768, 256, 0, stream>>>(xcpre, cw, cb, xc);
  // 3. x_dbl = xc @ x_proj_w^T (32768x40 stored in ldc=64; cols 40..63 unused)
  vgemm<64, 256, 0, 40><<<dim3(1024, 1), 256, 0, stream>>>(
      xc, xpw, xdbl, nullptr, nullptr, 64);
  // 4. selective scan (delta fused) -> y in-place over xc
  scan_k<<<256, 128, 0, stream>>>(xdbl, xc, zact, dtw, dtb, alog, Dp);
  // 5. out_proj: h1 = y @ out_proj_w^T (32768x128, K=256)
  vgemm<128, 256, 0, 128><<<dim3(1024, 1), 256, 0, stream>>>(
      xc, opw, h1, nullptr, nullptr, 128);
  // 6. fused strided down-conv -> hd (16384x128)
  down_k<<<2048, 128, 0, stream>>>(h1, wt, db, hd);
  // 7. LayerNorm -> output 0
  ln_k<<<16384, 64, 0, stream>>>(hd, lng, lnb, out);
  // 8. x_skip passthrough -> output 1 (overwrites hd staging)
  hipMemcpyAsync(out + 2097152, x, (size_t)16777216, hipMemcpyDeviceToDevice, stream);
}

// Round 4
// 614.378 us; speedup vs baseline: 1.0490x; 1.0490x over previous
//
#include <hip/hip_runtime.h>
#include <hip/hip_bf16.h>

// Problem dims (fixed by reference)
//   B=128, T=256, D_MODEL=128, D_INNER=256, D_STATE=16, D_CONV=4, DT_RANK=8
// I/O dtype: float32. All-VALU fp32 compute; xcpre/zact bf16 (budget <=1e-3).
// Outputs: h (128,128,128) then x_skip (128,256,128), fp32, concatenated.
//
// R4 change: scan_k restructured — x_dbl row (256t x 40) bulk-preloaded to
// LDS once (was: per-timestep global refill on the critical path), u/z
// register-prefetched at distance 2, zero barriers in the serial loop.

typedef __attribute__((ext_vector_type(4))) float f32x4;
using bf16 = __hip_bfloat16;

static __device__ __forceinline__ short f2s(float v) {
  union { bf16 b; short s; } u; u.b = (bf16)v; return u.s;
}
static __device__ __forceinline__ float s2f(short s) {
  union { short s; bf16 b; } u; u.s = s; return (float)u.b;
}

// ---------------------------------------------------------------------------
// VALU GEMM: C[row, gcol] = sum_k A[row,k] * W[gcol,k]   (W row-major N x K)
// Block: 32 rows x NCOLS cols, 256 threads. A-tile staged in LDS. MODE 0:
// fp32 store (ldc), guarded col<NSTORE. MODE 1: in_proj epilogue -> bf16
// xcpre (gc<256) / bf16 silu(z) (gc>=256).
// ---------------------------------------------------------------------------
template<int NCOLS, int K, int MODE, int NSTORE>
__global__ __launch_bounds__(256) void vgemm(const float* __restrict__ A,
                                             const float* __restrict__ W,
                                             float* __restrict__ C,
                                             short* __restrict__ xcpre,
                                             short* __restrict__ zact,
                                             int ldc) {
  constexpr int RPT = (32 * NCOLS) / 256;
  __shared__ float At[32][K];
  const int m0  = blockIdx.x * 32;
  const int tid = threadIdx.x;
  for (int idx = tid; idx < 32 * K; idx += 256) {
    int r = idx / K, k = idx % K;
    At[r][k] = A[(size_t)(m0 + r) * K + k];
  }
  __syncthreads();
  const int col  = tid % NCOLS;
  const int r0   = (tid / NCOLS) * RPT;
  const int gcol = blockIdx.y * NCOLS + col;
  if (col < NSTORE) {
    float acc[RPT];
#pragma unroll
    for (int r = 0; r < RPT; ++r) acc[r] = 0.f;
    const float* Wrow = W + (size_t)gcol * K;
    for (int k = 0; k < K; k += 4) {
      f32x4 w = *(const f32x4*)(Wrow + k);
#pragma unroll
      for (int r = 0; r < RPT; ++r) {
        const float* a = &At[r0 + r][k];
        acc[r] += a[0] * w[0] + a[1] * w[1] + a[2] * w[2] + a[3] * w[3];
      }
    }
    if (MODE == 0) {
#pragma unroll
      for (int r = 0; r < RPT; ++r)
        C[(size_t)(m0 + r0 + r) * ldc + gcol] = acc[r];
    } else {
#pragma unroll
      for (int r = 0; r < RPT; ++r) {
        const int row = m0 + r0 + r;
        if (gcol < 256) {
          xcpre[(size_t)row * 256 + gcol] = f2s(acc[r]);
        } else {
          float v = acc[r];
          zact[(size_t)row * 256 + (gcol - 256)] = f2s(v / (1.f + __expf(-v)));
        }
      }
    }
  }
}

// ---------------------------------------------------------------------------
// Depthwise causal conv (width 4, cross-correlation) + bias + silu.
// xcpre (B*T,256) bf16 -> xc (B*T,256) fp32.
// ---------------------------------------------------------------------------
__global__ __launch_bounds__(256) void conv_silu(const short* __restrict__ xcpre,
                                                 const float* __restrict__ cw,
                                                 const float* __restrict__ cb,
                                                 float* __restrict__ xc) {
  int idx = blockIdx.x * 256 + threadIdx.x;   // (b,t,d), d fastest
  int d = idx & 255;
  int t = (idx >> 8) & 255;
  int b = idx >> 16;
  float acc = cb[d];
#pragma unroll
  for (int i = 0; i < 4; ++i) {
    int ts = t - 3 + i;
    if (ts >= 0)
      acc += s2f(xcpre[(size_t)(b * 256 + ts) * 256 + d]) * cw[d * 4 + i];
  }
  xc[idx] = acc / (1.f + __expf(-acc));
}

// ---------------------------------------------------------------------------
// Selective scan, delta fused. Block = (batch, half of d_inner), 128 thr.
// R4: S = x_dbl[b, :, 0..39] (dt|B|C) fully staged in LDS up-front (40 KB,
// coalesced); serial loop has NO barriers and NO latency-critical global
// loads (u/z prefetched at distance 2). y in-place over xc.
// ---------------------------------------------------------------------------
__global__ __launch_bounds__(128) void scan_k(const float* __restrict__ xdbl,
                                              float* __restrict__ xcy,
                                              const short* __restrict__ zact,
                                              const float* __restrict__ dtw,
                                              const float* __restrict__ dtb,
                                              const float* __restrict__ alog,
                                              const float* __restrict__ Dp) {
  const int b = blockIdx.x >> 1;
  const int d = (blockIdx.x & 1) * 128 + threadIdx.x;
  __shared__ float S[256][40];                 // 40,960 B
  const size_t rb = (size_t)b * 256;
  for (int idx = threadIdx.x; idx < 256 * 40; idx += 128) {
    int r = idx / 40, c = idx - r * 40;
    S[r][c] = xdbl[(rb + r) * 64 + c];
  }
  float A[16];
#pragma unroll
  for (int n = 0; n < 16; ++n) A[n] = -__expf(alog[d * 16 + n]);
  float wdt[8];
#pragma unroll
  for (int j = 0; j < 8; ++j) wdt[j] = dtw[d * 8 + j];
  const float bdt = dtb[d];
  const float Dv  = Dp[d];
  float h[16];
#pragma unroll
  for (int n = 0; n < 16; ++n) h[n] = 0.f;
  // u/z prefetch, distance 2
  float u0 = xcy[rb * 256 + d];
  float u1 = xcy[(rb + 1) * 256 + d];
  float z0 = s2f(zact[rb * 256 + d]);
  float z1 = s2f(zact[(rb + 1) * 256 + d]);
  __syncthreads();
  for (int t = 0; t < 256; ++t) {
    const float u = u0, zs = z0;
    u0 = u1; z0 = z1;
    if (t + 2 < 256) {
      u1 = xcy[(rb + t + 2) * 256 + d];
      z1 = s2f(zact[(rb + t + 2) * 256 + d]);
    }
    const float* St = S[t];                    // broadcast LDS reads
    float dacc = bdt;
#pragma unroll
    for (int j = 0; j < 8; ++j) dacc += St[j] * wdt[j];
    const float delta = (dacc > 20.f) ? dacc : log1pf(__expf(dacc));
    const float du = delta * u;
    float yt = 0.f;
#pragma unroll
    for (int n = 0; n < 16; ++n) {
      float dA = __expf(delta * A[n]);
      h[n] = dA * h[n] + du * St[8 + n];
      yt += h[n] * St[24 + n];
    }
    xcy[(rb + t) * 256 + d] = (yt + u * Dv) * zs;
  }
}

// ---------------------------------------------------------------------------
// Transpose down_w (co,ci,k) -> WT[(k*128+ci)*128 + co].
// ---------------------------------------------------------------------------
__global__ __launch_bounds__(256) void prep_wcat(const float* __restrict__ dw,
                                                 float* __restrict__ wt) {
  int idx = blockIdx.x * 256 + threadIdx.x;   // 0..49151
  int co = idx & 127;
  int j  = idx >> 7;          // k*128+ci
  int k  = j >> 7;
  int ci = j & 127;
  wt[idx] = dw[(co * 128 + ci) * 3 + k];
}

// ---------------------------------------------------------------------------
// Fused strided down-conv: hd[b,to,co] = sum_{k,ci} h1[b,2to+k-1,ci]*w[co,ci,k]
// + db[co]. Block = (b, 8 'to'), 128 threads; 17 h1 rows in LDS.
// ---------------------------------------------------------------------------
__global__ __launch_bounds__(128) void down_k(const float* __restrict__ h1,
                                              const float* __restrict__ wt,
                                              const float* __restrict__ db,
                                              float* __restrict__ hd) {
  const int b   = blockIdx.x >> 4;
  const int to0 = (blockIdx.x & 15) * 8;
  const int co  = threadIdx.x;
  __shared__ float hs[17][128];
  const int tbase = 2 * to0 - 1;
#pragma unroll
  for (int i = 0; i < 17; ++i) {
    int t = tbase + i;
    hs[i][co] = (t >= 0 && t < 256) ? h1[(size_t)(b * 256 + t) * 128 + co] : 0.f;
  }
  __syncthreads();
  float acc[8];
  const float bias = db[co];
#pragma unroll
  for (int r = 0; r < 8; ++r) acc[r] = bias;
  for (int j = 0; j < 384; ++j) {
    float w = wt[j * 128 + co];
    int k = j >> 7, ci = j & 127;
#pragma unroll
    for (int r = 0; r < 8; ++r) acc[r] += hs[2 * r + k][ci] * w;
  }
#pragma unroll
  for (int r = 0; r < 8; ++r)
    hd[(size_t)(b * 128 + to0 + r) * 128 + co] = acc[r];
}

// ---------------------------------------------------------------------------
// LayerNorm over last dim (128), eps 1e-5. One wave per row, 2 cols/thread.
// ---------------------------------------------------------------------------
__global__ __launch_bounds__(64) void ln_k(const float* __restrict__ hd,
                                           const float* __restrict__ g,
                                           const float* __restrict__ be,
                                           float* __restrict__ out) {
  int row = blockIdx.x;
  const float* r = hd + (size_t)row * 128;
  float v0 = r[threadIdx.x];
  float v1 = r[threadIdx.x + 64];
  float s = v0 + v1;
#pragma unroll
  for (int off = 32; off; off >>= 1) s += __shfl_xor(s, off);
  float mu = s * (1.0f / 128.0f);
  float d0 = v0 - mu, d1 = v1 - mu;
  float vs = d0 * d0 + d1 * d1;
#pragma unroll
  for (int off = 32; off; off >>= 1) vs += __shfl_xor(vs, off);
  float rstd = rsqrtf(vs * (1.0f / 128.0f) + 1e-5f);
  out[(size_t)row * 128 + threadIdx.x]      = d0 * rstd * g[threadIdx.x] + be[threadIdx.x];
  out[(size_t)row * 128 + threadIdx.x + 64] = d1 * rstd * g[threadIdx.x + 64] + be[threadIdx.x + 64];
}

// ---------------------------------------------------------------------------
// Workspace layout (bytes), peak 92,471,296:
//   xcpre bf16 [0, 16M)  | zact bf16 [16M, 32M) | xc fp32 [32M, 64M) (y in-place)
//   xdbl fp32 [64M, 72M) | h1 fp32 [72M, 88M)   | WT fp32 [88M, +192K)
// hd staged in d_out's x_skip half, consumed by LN before the x_skip copy.
// ---------------------------------------------------------------------------
static const size_t O_XCPRE = 0;
static const size_t O_ZACT  = 16777216;
static const size_t O_XC    = 33554432;
static const size_t O_XDBL  = 67108864;
static const size_t O_H1    = 75497472;
static const size_t O_WT    = 92274688;   // end 92,471,296

extern "C" void kernel_launch(void* const* d_in, const int* in_sizes, int n_in,
                              void* d_out, int out_size, void* d_ws, size_t ws_size,
                              hipStream_t stream) {
  const float* x    = (const float*)d_in[0];
  const float* ipw  = (const float*)d_in[1];
  const float* cw   = (const float*)d_in[2];
  const float* cb   = (const float*)d_in[3];
  const float* xpw  = (const float*)d_in[4];
  const float* dtw  = (const float*)d_in[5];
  const float* dtb  = (const float*)d_in[6];
  const float* alog = (const float*)d_in[7];
  const float* Dp   = (const float*)d_in[8];
  const float* opw  = (const float*)d_in[9];
  const float* dw   = (const float*)d_in[10];
  const float* db   = (const float*)d_in[11];
  const float* lng  = (const float*)d_in[12];
  const float* lnb  = (const float*)d_in[13];

  char*  ws    = (char*)d_ws;
  short* xcpre = (short*)(ws + O_XCPRE);
  short* zact  = (short*)(ws + O_ZACT);
  float* xc    = (float*)(ws + O_XC);     // becomes y in-place after scan
  float* xdbl  = (float*)(ws + O_XDBL);
  float* h1    = (float*)(ws + O_H1);
  float* wt    = (float*)(ws + O_WT);
  float* out   = (float*)d_out;
  float* hd    = out + 2097152;           // staged in x_skip half of d_out

  // 0. transpose down_w
  prep_wcat<<<192, 256, 0, stream>>>(dw, wt);
  // 1. in_proj (32768x512, K=128) -> bf16 xcpre (cols 0..255), bf16 silu(z)
  vgemm<128, 128, 1, 128><<<dim3(1024, 4), 256, 0, stream>>>(
      x, ipw, nullptr, xcpre, zact, 0);
  // 2. depthwise causal conv + silu -> xc (fp32)
  conv_silu<<<32768, 256, 0, stream>>>(xcpre, cw, cb, xc);
  // 3. x_dbl = xc @ x_proj_w^T (32768x40 stored in ldc=64; cols 40..63 unused)
  vgemm<64, 256, 0, 40><<<dim3(1024, 1), 256, 0, stream>>>(
      xc, xpw, xdbl, nullptr, nullptr, 64);
  // 4. selective scan (delta fused) -> y in-place over xc
  scan_k<<<256, 128, 0, stream>>>(xdbl, xc, zact, dtw, dtb, alog, Dp);
  // 5. out_proj: h1 = y @ out_proj_w^T (32768x128, K=256)
  vgemm<128, 256, 0, 128><<<dim3(1024, 1), 256, 0, stream>>>(
      xc, opw, h1, nullptr, nullptr, 128);
  // 6. fused strided down-conv -> hd (16384x128)
  down_k<<<2048, 128, 0, stream>>>(h1, wt, db, hd);
  // 7. LayerNorm -> output 0
  ln_k<<<16384, 64, 0, stream>>>(hd, lng, lnb, out);
  // 8. x_skip passthrough -> output 1 (overwrites hd staging)
  hipMemcpyAsync(out + 2097152, x, (size_t)16777216, hipMemcpyDeviceToDevice, stream);
}

// Round 5
// 496.565 us; speedup vs baseline: 1.2979x; 1.2373x over previous
//
#include <hip/hip_runtime.h>
#include <hip/hip_bf16.h>

// Problem dims (fixed by reference)
//   B=128, T=256, D_MODEL=128, D_INNER=256, D_STATE=16, D_CONV=4, DT_RANK=8
// I/O dtype: float32. All-VALU fp32 compute; xcpre/zact bf16 (budget <=1e-3).
// Outputs: h (128,128,128) then x_skip (128,256,128), fp32, concatenated.
//
// R5 change (scan_k only): scan parallelism is structurally 512 waves
// (2/CU) -> latency-bound. Removed all latency from the serial chain:
// u/z chunk-prefetched into register double-buffers (16-step chunks),
// S read as float4 (ds_read_b128) in a fully-unrolled 16-step body.

typedef __attribute__((ext_vector_type(4))) float f32x4;
using bf16 = __hip_bfloat16;

static __device__ __forceinline__ short f2s(float v) {
  union { bf16 b; short s; } u; u.b = (bf16)v; return u.s;
}
static __device__ __forceinline__ float s2f(short s) {
  union { short s; bf16 b; } u; u.s = s; return (float)u.b;
}

// ---------------------------------------------------------------------------
// VALU GEMM: C[row, gcol] = sum_k A[row,k] * W[gcol,k]   (W row-major N x K)
// Block: 32 rows x NCOLS cols, 256 threads. A-tile staged in LDS. MODE 0:
// fp32 store (ldc), guarded col<NSTORE. MODE 1: in_proj epilogue -> bf16
// xcpre (gc<256) / bf16 silu(z) (gc>=256).
// ---------------------------------------------------------------------------
template<int NCOLS, int K, int MODE, int NSTORE>
__global__ __launch_bounds__(256) void vgemm(const float* __restrict__ A,
                                             const float* __restrict__ W,
                                             float* __restrict__ C,
                                             short* __restrict__ xcpre,
                                             short* __restrict__ zact,
                                             int ldc) {
  constexpr int RPT = (32 * NCOLS) / 256;
  __shared__ float At[32][K];
  const int m0  = blockIdx.x * 32;
  const int tid = threadIdx.x;
  for (int idx = tid; idx < 32 * K; idx += 256) {
    int r = idx / K, k = idx % K;
    At[r][k] = A[(size_t)(m0 + r) * K + k];
  }
  __syncthreads();
  const int col  = tid % NCOLS;
  const int r0   = (tid / NCOLS) * RPT;
  const int gcol = blockIdx.y * NCOLS + col;
  if (col < NSTORE) {
    float acc[RPT];
#pragma unroll
    for (int r = 0; r < RPT; ++r) acc[r] = 0.f;
    const float* Wrow = W + (size_t)gcol * K;
    for (int k = 0; k < K; k += 4) {
      f32x4 w = *(const f32x4*)(Wrow + k);
#pragma unroll
      for (int r = 0; r < RPT; ++r) {
        const float* a = &At[r0 + r][k];
        acc[r] += a[0] * w[0] + a[1] * w[1] + a[2] * w[2] + a[3] * w[3];
      }
    }
    if (MODE == 0) {
#pragma unroll
      for (int r = 0; r < RPT; ++r)
        C[(size_t)(m0 + r0 + r) * ldc + gcol] = acc[r];
    } else {
#pragma unroll
      for (int r = 0; r < RPT; ++r) {
        const int row = m0 + r0 + r;
        if (gcol < 256) {
          xcpre[(size_t)row * 256 + gcol] = f2s(acc[r]);
        } else {
          float v = acc[r];
          zact[(size_t)row * 256 + (gcol - 256)] = f2s(v / (1.f + __expf(-v)));
        }
      }
    }
  }
}

// ---------------------------------------------------------------------------
// Depthwise causal conv (width 4, cross-correlation) + bias + silu.
// xcpre (B*T,256) bf16 -> xc (B*T,256) fp32.
// ---------------------------------------------------------------------------
__global__ __launch_bounds__(256) void conv_silu(const short* __restrict__ xcpre,
                                                 const float* __restrict__ cw,
                                                 const float* __restrict__ cb,
                                                 float* __restrict__ xc) {
  int idx = blockIdx.x * 256 + threadIdx.x;   // (b,t,d), d fastest
  int d = idx & 255;
  int t = (idx >> 8) & 255;
  int b = idx >> 16;
  float acc = cb[d];
#pragma unroll
  for (int i = 0; i < 4; ++i) {
    int ts = t - 3 + i;
    if (ts >= 0)
      acc += s2f(xcpre[(size_t)(b * 256 + ts) * 256 + d]) * cw[d * 4 + i];
  }
  xc[idx] = acc / (1.f + __expf(-acc));
}

// ---------------------------------------------------------------------------
// Selective scan, delta fused. Block = (batch, half of d_inner), 128 thr.
// R5: u/z chunk-prefetched (16-step chunks, register double-buffer; loads
// for chunk c+1 in flight during chunk c's compute). S (dt|B|C per t) in
// LDS, read as float4 broadcast in a fully-unrolled inner body. Zero
// barriers and zero latency-critical memory ops in the serial loop.
// y in-place over xc.
// ---------------------------------------------------------------------------
__global__ __launch_bounds__(128, 1) void scan_k(const float* __restrict__ xdbl,
                                                 float* __restrict__ xcy,
                                                 const short* __restrict__ zact,
                                                 const float* __restrict__ dtw,
                                                 const float* __restrict__ dtb,
                                                 const float* __restrict__ alog,
                                                 const float* __restrict__ Dp) {
  const int b = blockIdx.x >> 1;
  const int d = (blockIdx.x & 1) * 128 + threadIdx.x;
  __shared__ float S[256][40];                 // 40,960 B
  const size_t rb = (size_t)b * 256;
  // coalesced float4 preload of S: 2560 float4s over 128 threads
  for (int i = threadIdx.x; i < 2560; i += 128) {
    int row = i / 10, c4 = i - row * 10;
    f32x4 v = *(const f32x4*)(xdbl + (rb + row) * 64 + c4 * 4);
    *(f32x4*)(&S[row][c4 * 4]) = v;
  }
  float A[16];
#pragma unroll
  for (int n = 0; n < 16; ++n) A[n] = -__expf(alog[d * 16 + n]);
  float wdt[8];
#pragma unroll
  for (int j = 0; j < 8; ++j) wdt[j] = dtw[d * 8 + j];
  const float bdt = dtb[d];
  const float Dv  = Dp[d];
  float h[16];
#pragma unroll
  for (int n = 0; n < 16; ++n) h[n] = 0.f;
  // u/z register double-buffer, 16-step chunks
  float uc[16], zc[16], un[16], zn[16];
  {
    const size_t base = rb * 256 + d;
#pragma unroll
    for (int i = 0; i < 16; ++i) {
      un[i] = xcy[base + (size_t)i * 256];
      zn[i] = s2f(zact[base + (size_t)i * 256]);
    }
  }
  __syncthreads();
  for (int c = 0; c < 16; ++c) {
    // consume prefetched chunk (waits vmcnt here), then launch next chunk
#pragma unroll
    for (int i = 0; i < 16; ++i) { uc[i] = un[i]; zc[i] = zn[i]; }
    if (c + 1 < 16) {
      const size_t base = (rb + (size_t)(c + 1) * 16) * 256 + d;
#pragma unroll
      for (int i = 0; i < 16; ++i) {
        un[i] = xcy[base + (size_t)i * 256];
        zn[i] = s2f(zact[base + (size_t)i * 256]);
      }
    }
#pragma unroll
    for (int tt = 0; tt < 16; ++tt) {
      const int t = c * 16 + tt;
      const f32x4* Sv = (const f32x4*)(&S[t][0]);
      f32x4 s0 = Sv[0], s1 = Sv[1];            // dt[0..7]
      f32x4 b0 = Sv[2], b1 = Sv[3], b2 = Sv[4], b3 = Sv[5];   // B[0..15]
      f32x4 c0 = Sv[6], c1 = Sv[7], c2 = Sv[8], c3 = Sv[9];   // C[0..15]
      float dacc = bdt
        + s0[0] * wdt[0] + s0[1] * wdt[1] + s0[2] * wdt[2] + s0[3] * wdt[3]
        + s1[0] * wdt[4] + s1[1] * wdt[5] + s1[2] * wdt[6] + s1[3] * wdt[7];
      const float delta = (dacc > 20.f) ? dacc : __logf(1.f + __expf(dacc));
      const float u  = uc[tt];
      const float du = delta * u;
      const float* Bt = (const float*)&b0;     // b0..b3 contiguous? no — index explicitly
      float yt0 = 0.f, yt1 = 0.f, yt2 = 0.f, yt3 = 0.f;
      float Bv[16] = { b0[0], b0[1], b0[2], b0[3], b1[0], b1[1], b1[2], b1[3],
                       b2[0], b2[1], b2[2], b2[3], b3[0], b3[1], b3[2], b3[3] };
      float Cv[16] = { c0[0], c0[1], c0[2], c0[3], c1[0], c1[1], c1[2], c1[3],
                       c2[0], c2[1], c2[2], c2[3], c3[0], c3[1], c3[2], c3[3] };
      (void)Bt;
#pragma unroll
      for (int n = 0; n < 16; ++n) {
        float dA = __expf(delta * A[n]);
        h[n] = dA * h[n] + du * Bv[n];
        float p = h[n] * Cv[n];
        if ((n & 3) == 0) yt0 += p;
        else if ((n & 3) == 1) yt1 += p;
        else if ((n & 3) == 2) yt2 += p;
        else yt3 += p;
      }
      const float yt = (yt0 + yt1) + (yt2 + yt3);
      xcy[(rb + t) * 256 + d] = (yt + u * Dv) * zc[tt];
    }
  }
}

// ---------------------------------------------------------------------------
// Transpose down_w (co,ci,k) -> WT[(k*128+ci)*128 + co].
// ---------------------------------------------------------------------------
__global__ __launch_bounds__(256) void prep_wcat(const float* __restrict__ dw,
                                                 float* __restrict__ wt) {
  int idx = blockIdx.x * 256 + threadIdx.x;   // 0..49151
  int co = idx & 127;
  int j  = idx >> 7;          // k*128+ci
  int k  = j >> 7;
  int ci = j & 127;
  wt[idx] = dw[(co * 128 + ci) * 3 + k];
}

// ---------------------------------------------------------------------------
// Fused strided down-conv: hd[b,to,co] = sum_{k,ci} h1[b,2to+k-1,ci]*w[co,ci,k]
// + db[co]. Block = (b, 8 'to'), 128 threads; 17 h1 rows in LDS.
// ---------------------------------------------------------------------------
__global__ __launch_bounds__(128) void down_k(const float* __restrict__ h1,
                                              const float* __restrict__ wt,
                                              const float* __restrict__ db,
                                              float* __restrict__ hd) {
  const int b   = blockIdx.x >> 4;
  const int to0 = (blockIdx.x & 15) * 8;
  const int co  = threadIdx.x;
  __shared__ float hs[17][128];
  const int tbase = 2 * to0 - 1;
#pragma unroll
  for (int i = 0; i < 17; ++i) {
    int t = tbase + i;
    hs[i][co] = (t >= 0 && t < 256) ? h1[(size_t)(b * 256 + t) * 128 + co] : 0.f;
  }
  __syncthreads();
  float acc[8];
  const float bias = db[co];
#pragma unroll
  for (int r = 0; r < 8; ++r) acc[r] = bias;
  for (int j = 0; j < 384; ++j) {
    float w = wt[j * 128 + co];
    int k = j >> 7, ci = j & 127;
#pragma unroll
    for (int r = 0; r < 8; ++r) acc[r] += hs[2 * r + k][ci] * w;
  }
#pragma unroll
  for (int r = 0; r < 8; ++r)
    hd[(size_t)(b * 128 + to0 + r) * 128 + co] = acc[r];
}

// ---------------------------------------------------------------------------
// LayerNorm over last dim (128), eps 1e-5. One wave per row, 2 cols/thread.
// ---------------------------------------------------------------------------
__global__ __launch_bounds__(64) void ln_k(const float* __restrict__ hd,
                                           const float* __restrict__ g,
                                           const float* __restrict__ be,
                                           float* __restrict__ out) {
  int row = blockIdx.x;
  const float* r = hd + (size_t)row * 128;
  float v0 = r[threadIdx.x];
  float v1 = r[threadIdx.x + 64];
  float s = v0 + v1;
#pragma unroll
  for (int off = 32; off; off >>= 1) s += __shfl_xor(s, off);
  float mu = s * (1.0f / 128.0f);
  float d0 = v0 - mu, d1 = v1 - mu;
  float vs = d0 * d0 + d1 * d1;
#pragma unroll
  for (int off = 32; off; off >>= 1) vs += __shfl_xor(vs, off);
  float rstd = rsqrtf(vs * (1.0f / 128.0f) + 1e-5f);
  out[(size_t)row * 128 + threadIdx.x]      = d0 * rstd * g[threadIdx.x] + be[threadIdx.x];
  out[(size_t)row * 128 + threadIdx.x + 64] = d1 * rstd * g[threadIdx.x + 64] + be[threadIdx.x + 64];
}

// ---------------------------------------------------------------------------
// Workspace layout (bytes), peak 92,471,296:
//   xcpre bf16 [0, 16M)  | zact bf16 [16M, 32M) | xc fp32 [32M, 64M) (y in-place)
//   xdbl fp32 [64M, 72M) | h1 fp32 [72M, 88M)   | WT fp32 [88M, +192K)
// hd staged in d_out's x_skip half, consumed by LN before the x_skip copy.
// ---------------------------------------------------------------------------
static const size_t O_XCPRE = 0;
static const size_t O_ZACT  = 16777216;
static const size_t O_XC    = 33554432;
static const size_t O_XDBL  = 67108864;
static const size_t O_H1    = 75497472;
static const size_t O_WT    = 92274688;   // end 92,471,296

extern "C" void kernel_launch(void* const* d_in, const int* in_sizes, int n_in,
                              void* d_out, int out_size, void* d_ws, size_t ws_size,
                              hipStream_t stream) {
  const float* x    = (const float*)d_in[0];
  const float* ipw  = (const float*)d_in[1];
  const float* cw   = (const float*)d_in[2];
  const float* cb   = (const float*)d_in[3];
  const float* xpw  = (const float*)d_in[4];
  const float* dtw  = (const float*)d_in[5];
  const float* dtb  = (const float*)d_in[6];
  const float* alog = (const float*)d_in[7];
  const float* Dp   = (const float*)d_in[8];
  const float* opw  = (const float*)d_in[9];
  const float* dw   = (const float*)d_in[10];
  const float* db   = (const float*)d_in[11];
  const float* lng  = (const float*)d_in[12];
  const float* lnb  = (const float*)d_in[13];

  char*  ws    = (char*)d_ws;
  short* xcpre = (short*)(ws + O_XCPRE);
  short* zact  = (short*)(ws + O_ZACT);
  float* xc    = (float*)(ws + O_XC);     // becomes y in-place after scan
  float* xdbl  = (float*)(ws + O_XDBL);
  float* h1    = (float*)(ws + O_H1);
  float* wt    = (float*)(ws + O_WT);
  float* out   = (float*)d_out;
  float* hd    = out + 2097152;           // staged in x_skip half of d_out

  // 0. transpose down_w
  prep_wcat<<<192, 256, 0, stream>>>(dw, wt);
  // 1. in_proj (32768x512, K=128) -> bf16 xcpre (cols 0..255), bf16 silu(z)
  vgemm<128, 128, 1, 128><<<dim3(1024, 4), 256, 0, stream>>>(
      x, ipw, nullptr, xcpre, zact, 0);
  // 2. depthwise causal conv + silu -> xc (fp32)
  conv_silu<<<32768, 256, 0, stream>>>(xcpre, cw, cb, xc);
  // 3. x_dbl = xc @ x_proj_w^T (32768x40 stored in ldc=64; cols 40..63 unused)
  vgemm<64, 256, 0, 40><<<dim3(1024, 1), 256, 0, stream>>>(
      xc, xpw, xdbl, nullptr, nullptr, 64);
  // 4. selective scan (delta fused) -> y in-place over xc
  scan_k<<<256, 128, 0, stream>>>(xdbl, xc, zact, dtw, dtb, alog, Dp);
  // 5. out_proj: h1 = y @ out_proj_w^T (32768x128, K=256)
  vgemm<128, 256, 0, 128><<<dim3(1024, 1), 256, 0, stream>>>(
      xc, opw, h1, nullptr, nullptr, 128);
  // 6. fused strided down-conv -> hd (16384x128)
  down_k<<<2048, 128, 0, stream>>>(h1, wt, db, hd);
  // 7. LayerNorm -> output 0
  ln_k<<<16384, 64, 0, stream>>>(hd, lng, lnb, out);
  // 8. x_skip passthrough -> output 1 (overwrites hd staging)
  hipMemcpyAsync(out + 2097152, x, (size_t)16777216, hipMemcpyDeviceToDevice, stream);
}

// Round 6
// 389.263 us; speedup vs baseline: 1.6556x; 1.2757x over previous
//
#include <hip/hip_runtime.h>
#include <hip/hip_bf16.h>

// Problem dims (fixed by reference)
//   B=128, T=256, D_MODEL=128, D_INNER=256, D_STATE=16, D_CONV=4, DT_RANK=8
// I/O dtype: float32. R6: in_proj/out_proj on MFMA bf16 (round-2 structure,
// now with workspace held to 84.3MB <= proven-safe 92.5MB — round-2's fail
// is attributed to ws overflow at 96.8MB, not the MFMA mapping).
// Outputs: h (128,128,128) then x_skip (128,256,128), fp32, concatenated.

typedef __attribute__((ext_vector_type(8))) short bf16x8;
typedef __attribute__((ext_vector_type(4))) short bf16x4;
typedef __attribute__((ext_vector_type(4))) float f32x4;
using bf16 = __hip_bfloat16;

static __device__ __forceinline__ short f2s(float v) {
  union { bf16 b; short s; } u; u.b = (bf16)v; return u.s;
}
static __device__ __forceinline__ float s2f(short s) {
  union { short s; bf16 b; } u; u.s = s; return (float)u.b;
}

// ---------------------------------------------------------------------------
// fp32 -> bf16 convert for x (4,194,304 elems), 4/thread.
// ---------------------------------------------------------------------------
__global__ __launch_bounds__(256) void cvt_x(const float* __restrict__ x,
                                             short* __restrict__ xb) {
  int i = (blockIdx.x * 256 + threadIdx.x) * 4;
  f32x4 v = *(const f32x4*)(x + i);
  bf16x4 o;
  o[0] = f2s(v[0]); o[1] = f2s(v[1]); o[2] = f2s(v[2]); o[3] = f2s(v[3]);
  *(bf16x4*)(xb + i) = o;
}

// ---------------------------------------------------------------------------
// Weight prep: ipw(512x128)->bf16, opw(128x256)->bf16,
// down_w (co,ci,k) -> WT[(k*128+ci)*128+co] fp32.
// ---------------------------------------------------------------------------
__global__ __launch_bounds__(256) void prep_w(const float* __restrict__ ipw,
                                              const float* __restrict__ opw,
                                              const float* __restrict__ dw,
                                              short* __restrict__ ipwb,
                                              short* __restrict__ opwb,
                                              float* __restrict__ wt) {
  int idx = blockIdx.x * 256 + threadIdx.x;   // 0 .. 147455
  if (idx < 65536) {
    ipwb[idx] = f2s(ipw[idx]);
  } else if (idx < 98304) {
    int j = idx - 65536;
    opwb[j] = f2s(opw[j]);
  } else {
    int j = idx - 98304;          // (k*128+ci)*128 + co
    int co = j & 127;
    int p  = j >> 7;              // k*128+ci
    int k  = p >> 7;
    int ci = p & 127;
    wt[j] = dw[(co * 128 + ci) * 3 + k];
  }
}

// ---------------------------------------------------------------------------
// MFMA GEMM: C = A(MxK bf16) @ W(NxK bf16)^T. Block 256thr/4 waves, tile
// 64m x 64n, wave = 16 rows x 4 n-frags. mfma_f32_16x16x32_bf16 layouts:
//   A/B frag: row(lane&15), k = (lane>>4)*8 + j
//   C/D frag: col(lane&15), row = (lane>>4)*4 + reg
// MODE 0: fp32 store, ldc=N. MODE 1 (in_proj): col<256 -> bf16 xcpre,
// col>=256 -> bf16 silu -> zact.
// ---------------------------------------------------------------------------
template<int N, int K, int MODE>
__global__ __launch_bounds__(256) void mgemm(const short* __restrict__ A,
                                             const short* __restrict__ W,
                                             float* __restrict__ C,
                                             short* __restrict__ xcpre,
                                             short* __restrict__ zact) {
  const int m_base = blockIdx.x * 64;
  const int n_base = blockIdx.y * 64;
  const int wave = threadIdx.x >> 6;
  const int lane = threadIdx.x & 63;
  const int r16  = lane & 15;
  const int quad = lane >> 4;
  f32x4 acc[4] = {};
  const short* Ap = A + (size_t)(m_base + wave * 16 + r16) * K + quad * 8;
  const short* Wp = W + (size_t)(n_base + r16) * K + quad * 8;
#pragma unroll
  for (int k0 = 0; k0 < K; k0 += 32) {
    bf16x8 a = *(const bf16x8*)(Ap + k0);
#pragma unroll
    for (int j = 0; j < 4; ++j) {
      bf16x8 b = *(const bf16x8*)(Wp + (size_t)j * 16 * K + k0);
      acc[j] = __builtin_amdgcn_mfma_f32_16x16x32_bf16(a, b, acc[j], 0, 0, 0);
    }
  }
#pragma unroll
  for (int j = 0; j < 4; ++j) {
    const int col = n_base + j * 16 + r16;
#pragma unroll
    for (int r = 0; r < 4; ++r) {
      const int row = m_base + wave * 16 + quad * 4 + r;
      if (MODE == 0) {
        C[(size_t)row * N + col] = acc[j][r];
      } else {
        if (col < 256) {
          xcpre[(size_t)row * 256 + col] = f2s(acc[j][r]);
        } else {
          float v = acc[j][r];
          zact[(size_t)row * 256 + (col - 256)] = f2s(v / (1.f + __expf(-v)));
        }
      }
    }
  }
}

// ---------------------------------------------------------------------------
// VALU GEMM (kept for x_dbl): C[row,gcol] = sum_k A[row,k]*W[gcol,k].
// ---------------------------------------------------------------------------
template<int NCOLS, int K, int NSTORE>
__global__ __launch_bounds__(256) void vgemm(const float* __restrict__ A,
                                             const float* __restrict__ W,
                                             float* __restrict__ C,
                                             int ldc) {
  constexpr int RPT = (32 * NCOLS) / 256;
  __shared__ float At[32][K];
  const int m0  = blockIdx.x * 32;
  const int tid = threadIdx.x;
  for (int idx = tid; idx < 32 * K; idx += 256) {
    int r = idx / K, k = idx % K;
    At[r][k] = A[(size_t)(m0 + r) * K + k];
  }
  __syncthreads();
  const int col  = tid % NCOLS;
  const int r0   = (tid / NCOLS) * RPT;
  const int gcol = blockIdx.y * NCOLS + col;
  if (col < NSTORE) {
    float acc[RPT];
#pragma unroll
    for (int r = 0; r < RPT; ++r) acc[r] = 0.f;
    const float* Wrow = W + (size_t)gcol * K;
    for (int k = 0; k < K; k += 4) {
      f32x4 w = *(const f32x4*)(Wrow + k);
#pragma unroll
      for (int r = 0; r < RPT; ++r) {
        const float* a = &At[r0 + r][k];
        acc[r] += a[0] * w[0] + a[1] * w[1] + a[2] * w[2] + a[3] * w[3];
      }
    }
#pragma unroll
    for (int r = 0; r < RPT; ++r)
      C[(size_t)(m0 + r0 + r) * ldc + gcol] = acc[r];
  }
}

// ---------------------------------------------------------------------------
// Depthwise causal conv (width 4) + bias + silu. xcpre bf16 -> xc fp32.
// ---------------------------------------------------------------------------
__global__ __launch_bounds__(256) void conv_silu(const short* __restrict__ xcpre,
                                                 const float* __restrict__ cw,
                                                 const float* __restrict__ cb,
                                                 float* __restrict__ xc) {
  int idx = blockIdx.x * 256 + threadIdx.x;   // (b,t,d), d fastest
  int d = idx & 255;
  int t = (idx >> 8) & 255;
  int b = idx >> 16;
  float acc = cb[d];
#pragma unroll
  for (int i = 0; i < 4; ++i) {
    int ts = t - 3 + i;
    if (ts >= 0)
      acc += s2f(xcpre[(size_t)(b * 256 + ts) * 256 + d]) * cw[d * 4 + i];
  }
  xc[idx] = acc / (1.f + __expf(-acc));
}

// ---------------------------------------------------------------------------
// Selective scan, delta fused (R5 structure). R6: y written as bf16 to yb
// (feeds the MFMA out_proj). u read from fp32 xc.
// ---------------------------------------------------------------------------
__global__ __launch_bounds__(128, 1) void scan_k(const float* __restrict__ xdbl,
                                                 const float* __restrict__ xcu,
                                                 short* __restrict__ yb,
                                                 const short* __restrict__ zact,
                                                 const float* __restrict__ dtw,
                                                 const float* __restrict__ dtb,
                                                 const float* __restrict__ alog,
                                                 const float* __restrict__ Dp) {
  const int b = blockIdx.x >> 1;
  const int d = (blockIdx.x & 1) * 128 + threadIdx.x;
  __shared__ float S[256][40];                 // 40,960 B
  const size_t rb = (size_t)b * 256;
  for (int i = threadIdx.x; i < 2560; i += 128) {
    int row = i / 10, c4 = i - row * 10;
    f32x4 v = *(const f32x4*)(xdbl + (rb + row) * 64 + c4 * 4);
    *(f32x4*)(&S[row][c4 * 4]) = v;
  }
  float A[16];
#pragma unroll
  for (int n = 0; n < 16; ++n) A[n] = -__expf(alog[d * 16 + n]);
  float wdt[8];
#pragma unroll
  for (int j = 0; j < 8; ++j) wdt[j] = dtw[d * 8 + j];
  const float bdt = dtb[d];
  const float Dv  = Dp[d];
  float h[16];
#pragma unroll
  for (int n = 0; n < 16; ++n) h[n] = 0.f;
  float uc[16], zc[16], un[16], zn[16];
  {
    const size_t base = rb * 256 + d;
#pragma unroll
    for (int i = 0; i < 16; ++i) {
      un[i] = xcu[base + (size_t)i * 256];
      zn[i] = s2f(zact[base + (size_t)i * 256]);
    }
  }
  __syncthreads();
  for (int c = 0; c < 16; ++c) {
#pragma unroll
    for (int i = 0; i < 16; ++i) { uc[i] = un[i]; zc[i] = zn[i]; }
    if (c + 1 < 16) {
      const size_t base = (rb + (size_t)(c + 1) * 16) * 256 + d;
#pragma unroll
      for (int i = 0; i < 16; ++i) {
        un[i] = xcu[base + (size_t)i * 256];
        zn[i] = s2f(zact[base + (size_t)i * 256]);
      }
    }
#pragma unroll
    for (int tt = 0; tt < 16; ++tt) {
      const int t = c * 16 + tt;
      const f32x4* Sv = (const f32x4*)(&S[t][0]);
      f32x4 s0 = Sv[0], s1 = Sv[1];
      f32x4 b0 = Sv[2], b1 = Sv[3], b2 = Sv[4], b3 = Sv[5];
      f32x4 c0 = Sv[6], c1 = Sv[7], c2 = Sv[8], c3 = Sv[9];
      float dacc = bdt
        + s0[0] * wdt[0] + s0[1] * wdt[1] + s0[2] * wdt[2] + s0[3] * wdt[3]
        + s1[0] * wdt[4] + s1[1] * wdt[5] + s1[2] * wdt[6] + s1[3] * wdt[7];
      const float delta = (dacc > 20.f) ? dacc : __logf(1.f + __expf(dacc));
      const float u  = uc[tt];
      const float du = delta * u;
      float yt0 = 0.f, yt1 = 0.f, yt2 = 0.f, yt3 = 0.f;
      float Bv[16] = { b0[0], b0[1], b0[2], b0[3], b1[0], b1[1], b1[2], b1[3],
                       b2[0], b2[1], b2[2], b2[3], b3[0], b3[1], b3[2], b3[3] };
      float Cv[16] = { c0[0], c0[1], c0[2], c0[3], c1[0], c1[1], c1[2], c1[3],
                       c2[0], c2[1], c2[2], c2[3], c3[0], c3[1], c3[2], c3[3] };
#pragma unroll
      for (int n = 0; n < 16; ++n) {
        float dA = __expf(delta * A[n]);
        h[n] = dA * h[n] + du * Bv[n];
        float p = h[n] * Cv[n];
        if ((n & 3) == 0) yt0 += p;
        else if ((n & 3) == 1) yt1 += p;
        else if ((n & 3) == 2) yt2 += p;
        else yt3 += p;
      }
      const float yt = (yt0 + yt1) + (yt2 + yt3);
      yb[(rb + t) * 256 + d] = f2s((yt + u * Dv) * zc[tt]);
    }
  }
}

// ---------------------------------------------------------------------------
// Fused strided down-conv: hd[b,to,co] = sum_{k,ci} h1[b,2to+k-1,ci]*w[co,ci,k]
// + db[co]. Block = (b, 8 'to'), 128 threads; 17 h1 rows in LDS.
// ---------------------------------------------------------------------------
__global__ __launch_bounds__(128) void down_k(const float* __restrict__ h1,
                                              const float* __restrict__ wt,
                                              const float* __restrict__ db,
                                              float* __restrict__ hd) {
  const int b   = blockIdx.x >> 4;
  const int to0 = (blockIdx.x & 15) * 8;
  const int co  = threadIdx.x;
  __shared__ float hs[17][128];
  const int tbase = 2 * to0 - 1;
#pragma unroll
  for (int i = 0; i < 17; ++i) {
    int t = tbase + i;
    hs[i][co] = (t >= 0 && t < 256) ? h1[(size_t)(b * 256 + t) * 128 + co] : 0.f;
  }
  __syncthreads();
  float acc[8];
  const float bias = db[co];
#pragma unroll
  for (int r = 0; r < 8; ++r) acc[r] = bias;
  for (int j = 0; j < 384; ++j) {
    float w = wt[j * 128 + co];
    int k = j >> 7, ci = j & 127;
#pragma unroll
    for (int r = 0; r < 8; ++r) acc[r] += hs[2 * r + k][ci] * w;
  }
#pragma unroll
  for (int r = 0; r < 8; ++r)
    hd[(size_t)(b * 128 + to0 + r) * 128 + co] = acc[r];
}

// ---------------------------------------------------------------------------
// LayerNorm over last dim (128), eps 1e-5. One wave per row, 2 cols/thread.
// ---------------------------------------------------------------------------
__global__ __launch_bounds__(64) void ln_k(const float* __restrict__ hd,
                                           const float* __restrict__ g,
                                           const float* __restrict__ be,
                                           float* __restrict__ out) {
  int row = blockIdx.x;
  const float* r = hd + (size_t)row * 128;
  float v0 = r[threadIdx.x];
  float v1 = r[threadIdx.x + 64];
  float s = v0 + v1;
#pragma unroll
  for (int off = 32; off; off >>= 1) s += __shfl_xor(s, off);
  float mu = s * (1.0f / 128.0f);
  float d0 = v0 - mu, d1 = v1 - mu;
  float vs = d0 * d0 + d1 * d1;
#pragma unroll
  for (int off = 32; off; off >>= 1) vs += __shfl_xor(vs, off);
  float rstd = rsqrtf(vs * (1.0f / 128.0f) + 1e-5f);
  out[(size_t)row * 128 + threadIdx.x]      = d0 * rstd * g[threadIdx.x] + be[threadIdx.x];
  out[(size_t)row * 128 + threadIdx.x + 64] = d1 * rstd * g[threadIdx.x + 64] + be[threadIdx.x + 64];
}

// ---------------------------------------------------------------------------
// Workspace layout (bytes), peak 84,279,296 (<= proven-safe 92,471,296):
//   [0,16M)      xcpre bf16 (in_proj out) -> reused as yb bf16 (scan out)
//   [16M,32M)    zact bf16
//   [32M,64M)    xc fp32 (conv out; u for scan) -> first 16MB reused as h1
//   [64M,72M)    xdbl fp32
//   [72M,80M)    xb bf16 (x converted; dead after in_proj)
//   [80M+...]    ipwb bf16 | opwb bf16 | wt fp32
// hd staged in d_out's x_skip half, consumed by LN before the x_skip copy.
// ---------------------------------------------------------------------------
static const size_t O_XCPRE = 0;            // also yb
static const size_t O_ZACT  = 16777216;
static const size_t O_XC    = 33554432;     // also h1 (first 16MB)
static const size_t O_XDBL  = 67108864;
static const size_t O_XB    = 75497472;
static const size_t O_IPWB  = 83886080;     // 131,072 B
static const size_t O_OPWB  = 84017152;     //  65,536 B
static const size_t O_WT    = 84082688;     // 196,608 B -> end 84,279,296

extern "C" void kernel_launch(void* const* d_in, const int* in_sizes, int n_in,
                              void* d_out, int out_size, void* d_ws, size_t ws_size,
                              hipStream_t stream) {
  const float* x    = (const float*)d_in[0];
  const float* ipw  = (const float*)d_in[1];
  const float* cw   = (const float*)d_in[2];
  const float* cb   = (const float*)d_in[3];
  const float* xpw  = (const float*)d_in[4];
  const float* dtw  = (const float*)d_in[5];
  const float* dtb  = (const float*)d_in[6];
  const float* alog = (const float*)d_in[7];
  const float* Dp   = (const float*)d_in[8];
  const float* opw  = (const float*)d_in[9];
  const float* dw   = (const float*)d_in[10];
  const float* db   = (const float*)d_in[11];
  const float* lng  = (const float*)d_in[12];
  const float* lnb  = (const float*)d_in[13];

  char*  ws    = (char*)d_ws;
  short* xcpre = (short*)(ws + O_XCPRE);
  short* yb    = (short*)(ws + O_XCPRE);  // alias (xcpre dead after conv)
  short* zact  = (short*)(ws + O_ZACT);
  float* xc    = (float*)(ws + O_XC);
  float* h1    = (float*)(ws + O_XC);     // alias (xc dead after scan)
  float* xdbl  = (float*)(ws + O_XDBL);
  short* xb    = (short*)(ws + O_XB);
  short* ipwb  = (short*)(ws + O_IPWB);
  short* opwb  = (short*)(ws + O_OPWB);
  float* wt    = (float*)(ws + O_WT);
  float* out   = (float*)d_out;
  float* hd    = out + 2097152;           // staged in x_skip half of d_out

  // 0. conversions / weight prep
  cvt_x<<<4096, 256, 0, stream>>>(x, xb);
  prep_w<<<576, 256, 0, stream>>>(ipw, opw, dw, ipwb, opwb, wt);
  // 1. in_proj MFMA (32768x512, K=128) -> bf16 xcpre + bf16 silu(z)
  mgemm<512, 128, 1><<<dim3(512, 8), 256, 0, stream>>>(
      xb, ipwb, nullptr, xcpre, zact);
  // 2. depthwise causal conv + silu -> xc (fp32)
  conv_silu<<<32768, 256, 0, stream>>>(xcpre, cw, cb, xc);
  // 3. x_dbl = xc @ x_proj_w^T (32768x40 in ldc=64)
  vgemm<64, 256, 40><<<dim3(1024, 1), 256, 0, stream>>>(xc, xpw, xdbl, 64);
  // 4. selective scan (delta fused) -> yb bf16
  scan_k<<<256, 128, 0, stream>>>(xdbl, xc, yb, zact, dtw, dtb, alog, Dp);
  // 5. out_proj MFMA: h1 = y @ out_proj_w^T (32768x128, K=256), fp32 out
  mgemm<128, 256, 0><<<dim3(512, 2), 256, 0, stream>>>(
      yb, opwb, h1, nullptr, nullptr);
  // 6. fused strided down-conv -> hd (16384x128)
  down_k<<<2048, 128, 0, stream>>>(h1, wt, db, hd);
  // 7. LayerNorm -> output 0
  ln_k<<<16384, 64, 0, stream>>>(hd, lng, lnb, out);
  // 8. x_skip passthrough -> output 1
  hipMemcpyAsync(out + 2097152, x, (size_t)16777216, hipMemcpyDeviceToDevice, stream);
}